// Round 1
// baseline (351.071 us; speedup 1.0000x reference)
//
#include <hip/hip_runtime.h>

#define D 64
#define K 512
#define QTOT (8 * 16384)   // B*N = 131072 query vectors

// ---- prep: e_sq[k] = sum_d codebook[k][d]^2 ----
__global__ void esq_kernel(const float* __restrict__ cb, float* __restrict__ esq) {
    int k = blockIdx.x * blockDim.x + threadIdx.x;
    if (k < K) {
        float s = 0.f;
        #pragma unroll
        for (int i = 0; i < D; ++i) {
            float v = cb[k * D + i];
            s = fmaf(v, v, s);
        }
        esq[k] = s;
    }
}

// ---- main: one query per lane, codebook via wave-uniform (scalar) loads ----
__global__ __launch_bounds__(256) void vq_kernel(const float* __restrict__ x,
                                                 const float* __restrict__ cb,
                                                 const float* __restrict__ esq,
                                                 float* __restrict__ out) {
    int q = blockIdx.x * blockDim.x + threadIdx.x;   // grid sized exactly

    // load this lane's query row into registers (16 x float4)
    float rx[D];
    const float4* xv = reinterpret_cast<const float4*>(x + (size_t)q * D);
    #pragma unroll
    for (int i = 0; i < D / 4; ++i) {
        float4 v = xv[i];
        rx[4 * i + 0] = v.x;
        rx[4 * i + 1] = v.y;
        rx[4 * i + 2] = v.z;
        rx[4 * i + 3] = v.w;
    }

    float best = 3.4e38f;
    int   bi   = 0;

    for (int k0 = 0; k0 < K; k0 += 8) {
        float acc[8];
        #pragma unroll
        for (int kk = 0; kk < 8; ++kk) acc[kk] = 0.f;

        // cross = x . e_k for 8 codes; cb addresses are wave-uniform -> s_load
        #pragma unroll
        for (int i0 = 0; i0 < D; i0 += 8) {
            // stage an 8x8 (code x dim) uniform tile; compiler keeps in SGPRs
            float e[8][8];
            #pragma unroll
            for (int kk = 0; kk < 8; ++kk)
                #pragma unroll
                for (int j = 0; j < 8; ++j)
                    e[kk][j] = cb[(size_t)(k0 + kk) * D + i0 + j];

            #pragma unroll
            for (int j = 0; j < 8; ++j) {
                float xi = rx[i0 + j];
                #pragma unroll
                for (int kk = 0; kk < 8; ++kk)
                    acc[kk] = fmaf(xi, e[kk][j], acc[kk]);
            }
        }

        // d2 proxy = e_sq - 2*cross  (x_sq constant per query; sqrt monotone)
        #pragma unroll
        for (int kk = 0; kk < 8; ++kk) {
            float d = fmaf(-2.f, acc[kk], esq[k0 + kk]);
            if (d < best) { best = d; bi = k0 + kk; }   // strict < => first index wins
        }
    }

    // emit codebook[bi] (codebook is L1/L2-hot)
    float4*       ov = reinterpret_cast<float4*>(out + (size_t)q * D);
    const float4* cv = reinterpret_cast<const float4*>(cb + (size_t)bi * D);
    #pragma unroll
    for (int i = 0; i < D / 4; ++i) ov[i] = cv[i];
}

extern "C" void kernel_launch(void* const* d_in, const int* in_sizes, int n_in,
                              void* d_out, int out_size, void* d_ws, size_t ws_size,
                              hipStream_t stream) {
    const float* x   = (const float*)d_in[0];   // [8,16384,64]
    const float* cb  = (const float*)d_in[1];   // [512,64]
    float*       out = (float*)d_out;           // [8,16384,1,64]
    float*       esq = (float*)d_ws;            // 512 floats scratch

    esq_kernel<<<2, 256, 0, stream>>>(cb, esq);
    vq_kernel<<<QTOT / 256, 256, 0, stream>>>(x, cb, esq, out);
}

// Round 2
// 147.898 us; speedup vs baseline: 2.3737x; 2.3737x over previous
//
#include <hip/hip_runtime.h>

#define D    64
#define K    512
#define QTOT (8 * 16384)   // B*N = 131072 query vectors
#define QPB  64            // queries per block (one per lane)
#define WPB  4             // waves per block (K-split)
#define KPW  (K / WPB)     // 128 codes per wave

// ---- prep: e_sq[k] = sum_d codebook[k][d]^2 ----
__global__ void esq_kernel(const float* __restrict__ cb, float* __restrict__ esq) {
    int k = blockIdx.x * blockDim.x + threadIdx.x;
    if (k < K) {
        float s = 0.f;
        #pragma unroll
        for (int i = 0; i < D; ++i) {
            float v = cb[k * D + i];
            s = fmaf(v, v, s);
        }
        esq[k] = s;
    }
}

// ---- main: 1 query/lane, codebook K-split across the 4 waves of a block ----
__global__ __launch_bounds__(256, 4) void vq_kernel(const float* __restrict__ x,
                                                    const float* __restrict__ cb,
                                                    const float* __restrict__ esq,
                                                    float* __restrict__ out) {
    const int tid  = threadIdx.x;
    const int lane = tid & 63;
    // wave id is wave-uniform; readfirstlane makes the compiler SEE that, so
    // codebook addresses derived from it stay scalar (s_load) after K-split.
    const int wv   = __builtin_amdgcn_readfirstlane(tid >> 6);
    const size_t q = (size_t)blockIdx.x * QPB + lane;

    __shared__ float sbest[WPB][QPB];
    __shared__ int   sbi[WPB][QPB];

    // query row -> 16 float4 registers (64 VGPRs)
    float4 rx[16];
    const float4* xv = reinterpret_cast<const float4*>(x + q * D);
    #pragma unroll
    for (int i = 0; i < 16; ++i) rx[i] = xv[i];

    const int kbase = wv * KPW;
    float best = 3.4e38f;
    int   bi   = kbase;

    for (int k0 = kbase; k0 < kbase + KPW; k0 += 4) {
        const float4* e0p = reinterpret_cast<const float4*>(cb + (size_t)(k0 + 0) * D);
        const float4* e1p = reinterpret_cast<const float4*>(cb + (size_t)(k0 + 1) * D);
        const float4* e2p = reinterpret_cast<const float4*>(cb + (size_t)(k0 + 2) * D);
        const float4* e3p = reinterpret_cast<const float4*>(cb + (size_t)(k0 + 3) * D);
        float a0 = 0.f, a1 = 0.f, a2 = 0.f, a3 = 0.f;
        #pragma unroll
        for (int i = 0; i < 16; ++i) {
            float4 xr = rx[i];
            float4 e0 = e0p[i], e1 = e1p[i], e2 = e2p[i], e3 = e3p[i];
            a0 = fmaf(xr.x, e0.x, a0); a0 = fmaf(xr.y, e0.y, a0);
            a0 = fmaf(xr.z, e0.z, a0); a0 = fmaf(xr.w, e0.w, a0);
            a1 = fmaf(xr.x, e1.x, a1); a1 = fmaf(xr.y, e1.y, a1);
            a1 = fmaf(xr.z, e1.z, a1); a1 = fmaf(xr.w, e1.w, a1);
            a2 = fmaf(xr.x, e2.x, a2); a2 = fmaf(xr.y, e2.y, a2);
            a2 = fmaf(xr.z, e2.z, a2); a2 = fmaf(xr.w, e2.w, a2);
            a3 = fmaf(xr.x, e3.x, a3); a3 = fmaf(xr.y, e3.y, a3);
            a3 = fmaf(xr.z, e3.z, a3); a3 = fmaf(xr.w, e3.w, a3);
        }
        // d2 proxy = e_sq - 2*cross (x_sq constant per query, sqrt monotone);
        // same fmaf chain/order as the passing round-1 kernel -> bit-identical.
        float d0 = fmaf(-2.f, a0, esq[k0 + 0]);
        float d1 = fmaf(-2.f, a1, esq[k0 + 1]);
        float d2 = fmaf(-2.f, a2, esq[k0 + 2]);
        float d3 = fmaf(-2.f, a3, esq[k0 + 3]);
        if (d0 < best) { best = d0; bi = k0 + 0; }   // strict < => first index wins
        if (d1 < best) { best = d1; bi = k0 + 1; }
        if (d2 < best) { best = d2; bi = k0 + 2; }
        if (d3 < best) { best = d3; bi = k0 + 3; }
    }

    sbest[wv][lane] = best;
    sbi[wv][lane]   = bi;
    __syncthreads();

    // combine the 4 waves' candidates; ascending w + strict < keeps the
    // globally-first index on ties (wave w covers codes [128w, 128w+128)).
    if (tid < QPB) {
        float b = sbest[0][lane];
        int   j = sbi[0][lane];
        #pragma unroll
        for (int w = 1; w < WPB; ++w) {
            float bw = sbest[w][lane];
            int   jw = sbi[w][lane];
            if (bw < b) { b = bw; j = jw; }
        }
        sbi[0][lane] = j;   // final index for query (block, lane)
    }
    __syncthreads();

    // coalesced epilogue: the block's 64 output rows are one contiguous 16 KB
    // region; 256 threads emit it as float4s (codebook reads are L1-hot).
    const float4* cbv  = reinterpret_cast<const float4*>(cb);
    float4*       outv = reinterpret_cast<float4*>(out) + (size_t)blockIdx.x * (QPB * D / 4);
    #pragma unroll
    for (int r = 0; r < 4; ++r) {
        int fi  = r * 256 + tid;      // 0..1023 flat float4 index in the block tile
        int row = fi >> 4;            // 16 float4s per row
        int col = fi & 15;
        outv[fi] = cbv[(size_t)sbi[0][row] * 16 + col];
    }
}

extern "C" void kernel_launch(void* const* d_in, const int* in_sizes, int n_in,
                              void* d_out, int out_size, void* d_ws, size_t ws_size,
                              hipStream_t stream) {
    const float* x   = (const float*)d_in[0];   // [8,16384,64]
    const float* cb  = (const float*)d_in[1];   // [512,64]
    float*       out = (float*)d_out;           // [8,16384,1,64]
    float*       esq = (float*)d_ws;            // 512 floats scratch

    esq_kernel<<<2, 256, 0, stream>>>(cb, esq);
    vq_kernel<<<QTOT / QPB, 256, 0, stream>>>(x, cb, esq, out);
}

// Round 4
// 61.896 us; speedup vs baseline: 5.6719x; 2.3894x over previous
//
#include <hip/hip_runtime.h>

#define D    64
#define K    512
#define QTOT (8 * 16384)
#define THR  0.008f

typedef __attribute__((ext_vector_type(8))) short short8;   // 8 bf16 payloads (4 VGPRs)
typedef __attribute__((ext_vector_type(4))) short short4v;  // 4 bf16 payloads (8 B)
typedef __attribute__((ext_vector_type(4))) float f32x4;

__device__ __forceinline__ unsigned short f2bf(float f) {   // fp32 -> bf16 (RNE)
    unsigned u = __builtin_bit_cast(unsigned, f);
    u = u + 0x7FFFu + ((u >> 16) & 1u);
    return (unsigned short)(u >> 16);
}
__device__ __forceinline__ float bf2f(unsigned short h) {
    unsigned u = ((unsigned)h) << 16;
    return __builtin_bit_cast(float, u);
}

// 512 thr/block, 8 waves x 64 queries; all prep done in-block (NO d_ws use).
__global__ __launch_bounds__(512) void vq_mfma(
        const float* __restrict__ x, const float* __restrict__ cb,
        float* __restrict__ out) {

    __shared__ unsigned short s_e[2][K * D];   // hi/lo split codebook, 2x64KB, XOR-swizzled
    __shared__ float s_esq[K];

    const int tid  = threadIdx.x;
    const int lane = tid & 63;
    const int qrow = lane & 15;                 // query col of C / code row of A
    const int kg   = lane >> 4;
    const int wv   = __builtin_amdgcn_readfirstlane(tid >> 6);
    const int qw   = blockIdx.x * 512 + wv * 64;   // wave's first query

    // ---- in-block prep: bf16 hi/lo split of cb -> LDS; byte ^= (row&7)<<4 swizzle ----
    const float4* cbv4 = (const float4*)cb;
    for (int c = tid; c < (K * D) / 4; c += 512) {
        float4 v = cbv4[c];
        float vv[4] = {v.x, v.y, v.z, v.w};
        short4v hi, lo;
        #pragma unroll
        for (int j = 0; j < 4; ++j) {
            unsigned short hb = f2bf(vv[j]);
            hi[j] = (short)hb;
            lo[j] = (short)f2bf(vv[j] - bf2f(hb));
        }
        int byteoff = c * 8;                    // 4 bf16 = 8 bytes
        int row     = byteoff >> 7;             // 128 B per code row
        int addr    = byteoff ^ ((row & 7) << 4);
        *(short4v*)((char*)s_e[0] + addr) = hi;
        *(short4v*)((char*)s_e[1] + addr) = lo;
    }
    {   // e_sq: one code per thread, ascending fmaf chain (matches rescan usage)
        float s = 0.f;
        #pragma unroll
        for (int d = 0; d < D; ++d) {
            float v = cb[tid * D + d];
            s = fmaf(v, v, s);
        }
        s_esq[tid] = s;
    }
    __syncthreads();

    // B-fragments: lane slot (kg, j) holds x[query][h*32 + kg*8 + j], split hi/lo.
    // A-slots use the SAME (kg, j) -> dim map, so the contraction is correct for
    // any hardware k-ordering (slots pair by equal k_hw <=> equal slot).
    short8 xh[4][2], xl[4][2];
    #pragma unroll
    for (int qt = 0; qt < 4; ++qt) {
        #pragma unroll
        for (int h = 0; h < 2; ++h) {
            const float* p = x + (size_t)(qw + qt * 16 + qrow) * D + h * 32 + kg * 8;
            float4 v0 = *(const float4*)p;
            float4 v1 = *(const float4*)(p + 4);
            float vv[8] = {v0.x, v0.y, v0.z, v0.w, v1.x, v1.y, v1.z, v1.w};
            short8 th, tl;
            #pragma unroll
            for (int j = 0; j < 8; ++j) {
                unsigned short hb = f2bf(vv[j]);
                th[j] = (short)hb;
                tl[j] = (short)f2bf(vv[j] - bf2f(hb));
            }
            xh[qt][h] = th;
            xl[qt][h] = tl;
        }
    }

    float m1[4], m2[4];
    int   i1[4];
    #pragma unroll
    for (int qt = 0; qt < 4; ++qt) { m1[qt] = 3.4e38f; m2[qt] = 3.4e38f; i1[qt] = 0; }

    const f32x4 zacc = {0.f, 0.f, 0.f, 0.f};

    for (int t = 0; t < 32; ++t) {
        const int row  = t * 16 + qrow;         // A-operand code row
        const int swz  = (row & 7) << 4;
        const int off0 = row * 128 + kg * 16;
        short8 eh0 = *(const short8*)((const char*)s_e[0] + ((off0     ) ^ swz));
        short8 eh1 = *(const short8*)((const char*)s_e[0] + ((off0 + 64) ^ swz));
        short8 el0 = *(const short8*)((const char*)s_e[1] + ((off0     ) ^ swz));
        short8 el1 = *(const short8*)((const char*)s_e[1] + ((off0 + 64) ^ swz));
        f32x4 eq = *(const f32x4*)(s_esq + t * 16 + kg * 4);

        #pragma unroll
        for (int qt = 0; qt < 4; ++qt) {
            f32x4 acc;
            // ONE asm block: s_nop guards cannot be separated from the MFMAs.
            // entry s_nop 3: VALU-write -> MFMA SrcA/B/C wait states
            // exit  s_nop 7 x2: MFMA write -> VALU read of D (16 >= required)
            // MFMA->MFMA same-D accumulation needs 0 wait states.
            asm volatile(
                "s_nop 3\n\t"
                "v_mfma_f32_16x16x32_bf16 %0, %1, %5, %9\n\t"
                "v_mfma_f32_16x16x32_bf16 %0, %2, %6, %0\n\t"
                "v_mfma_f32_16x16x32_bf16 %0, %1, %7, %0\n\t"
                "v_mfma_f32_16x16x32_bf16 %0, %2, %8, %0\n\t"
                "v_mfma_f32_16x16x32_bf16 %0, %3, %5, %0\n\t"
                "v_mfma_f32_16x16x32_bf16 %0, %4, %6, %0\n\t"
                "s_nop 7\n\t"
                "s_nop 7"
                : "=&v"(acc)
                : "v"(eh0), "v"(eh1), "v"(el0), "v"(el1),
                  "v"(xh[qt][0]), "v"(xh[qt][1]), "v"(xl[qt][0]), "v"(xl[qt][1]),
                  "v"(zacc));
            #pragma unroll
            for (int r = 0; r < 4; ++r) {
                float dd = fmaf(-2.f, acc[r], eq[r]);   // d2 proxy (x_sq const, sqrt monotone)
                int   kc = t * 16 + kg * 4 + r;
                bool  lt = dd < m1[qt];
                m2[qt] = lt ? m1[qt] : fminf(m2[qt], dd);
                m1[qt] = lt ? dd : m1[qt];
                i1[qt] = lt ? kc : i1[qt];
            }
        }
    }

    // combine (m1,i1,m2) across the 4 k-groups holding each query
    #pragma unroll
    for (int qt = 0; qt < 4; ++qt) {
        #pragma unroll
        for (int off = 16; off <= 32; off <<= 1) {
            float om1 = __shfl_xor(m1[qt], off, 64);
            float om2 = __shfl_xor(m2[qt], off, 64);
            int   oi  = __shfl_xor(i1[qt], off, 64);
            bool  lt  = om1 < m1[qt];
            float loser = lt ? m1[qt] : om1;
            m2[qt] = fminf(fminf(m2[qt], om2), loser);
            m1[qt] = lt ? om1 : m1[qt];
            i1[qt] = lt ? oi  : i1[qt];
        }
    }

    // exact fp32 rescan (identical chain to the passing round-2 kernel) when
    // top-2 gap <= THR >= 2*(bf16x3 error bound) -- guarantees fp32 argmin.
    // Ties in the approx path also land here (gap 0), restoring first-index.
    #pragma unroll
    for (int qt = 0; qt < 4; ++qt) {
        bool flag = (m2[qt] - m1[qt]) <= THR;
        unsigned long long mask = __ballot(flag && (lane < 16));
        while (mask) {
            int ql = __ffsll(mask) - 1;
            mask &= mask - 1;
            int qf = qw + qt * 16 + ql;                 // wave-uniform
            const float* xq = x + (size_t)qf * D;
            float bb = 3.4e38f;
            int   bq = 0;
            #pragma unroll 1
            for (int c0 = 0; c0 < 8; ++c0) {
                int kc = lane * 8 + c0;
                const float4* ep = (const float4*)(cb + (size_t)kc * D);
                float a = 0.f;
                #pragma unroll
                for (int i = 0; i < 16; ++i) {
                    float4 e = ep[i];
                    a = fmaf(xq[4 * i + 0], e.x, a);
                    a = fmaf(xq[4 * i + 1], e.y, a);
                    a = fmaf(xq[4 * i + 2], e.z, a);
                    a = fmaf(xq[4 * i + 3], e.w, a);
                }
                float dd = fmaf(-2.f, a, s_esq[kc]);
                if (dd < bb) { bb = dd; bq = kc; }      // ascending kc: first index wins
            }
            #pragma unroll
            for (int off = 1; off < 64; off <<= 1) {    // min-reduce, first-index tie-break
                float ob = __shfl_xor(bb, off, 64);
                int   oq = __shfl_xor(bq, off, 64);
                if (ob < bb || (ob == bb && oq < bq)) { bb = ob; bq = oq; }
            }
            if (qrow == ql) i1[qt] = bq;                // all 4 copies of this query
        }
    }

    // emit: out[q] = cb[i1]; lane (qrow,kg) writes 64 B of query qrow's row
    #pragma unroll
    for (int qt = 0; qt < 4; ++qt) {
        size_t q = (size_t)(qw + qt * 16 + qrow);
        const float4* src = (const float4*)(cb + (size_t)i1[qt] * D) + kg * 4;
        float4*       dst = (float4*)(out + q * D) + kg * 4;
        #pragma unroll
        for (int s = 0; s < 4; ++s) dst[s] = src[s];
    }
}

extern "C" void kernel_launch(void* const* d_in, const int* in_sizes, int n_in,
                              void* d_out, int out_size, void* d_ws, size_t ws_size,
                              hipStream_t stream) {
    const float* x   = (const float*)d_in[0];   // [8,16384,64]
    const float* cb  = (const float*)d_in[1];   // [512,64]
    float*       out = (float*)d_out;           // [8,16384,1,64]

    vq_mfma<<<QTOT / 512, 512, 0, stream>>>(x, cb, out);
}